// Round 1
// baseline (80.432 us; speedup 1.0000x reference)
//
#include <hip/hip_runtime.h>

// Problem constants (from reference setup_inputs): b=32, d=256, h=32, w=128
#define BB 32
#define DD 256
#define HW 4096            // h*w
#define DHW (DD * HW)      // 1048576 = 2^20
#define TOTAL (BB * DHW)   // 33554432
#define EPS 1e-5f

// ws layout (floats): [0,256) sum, [256,512) sumsq, [512] count,
//                     [520,776) scale, [776,1032) bias

__global__ void __launch_bounds__(256)
stats_kernel(const float* __restrict__ x, const int* __restrict__ mask,
             float* __restrict__ ws) {
    const int slice = blockIdx.x;          // 8192 slices
    const int b = slice >> 8;              // slice / 256
    const int d = slice & 255;
    const float4* xs = reinterpret_cast<const float4*>(
        x + (size_t)b * DHW + (size_t)d * HW);
    const int4* ms = reinterpret_cast<const int4*>(mask + b * HW);
    const int tid = threadIdx.x;

    float sum = 0.f, sq = 0.f, cnt = 0.f;
#pragma unroll
    for (int j = 0; j < 4; ++j) {
        const int v = j * 256 + tid;       // float4 index within the 4096-slice
        float4 xv = xs[v];
        int4 mv = ms[v];
        if (!mv.x) { sum += xv.x; sq += xv.x * xv.x; cnt += 1.f; }
        if (!mv.y) { sum += xv.y; sq += xv.y * xv.y; cnt += 1.f; }
        if (!mv.z) { sum += xv.z; sq += xv.z * xv.z; cnt += 1.f; }
        if (!mv.w) { sum += xv.w; sq += xv.w * xv.w; cnt += 1.f; }
    }

    // wave64 shuffle reduce
#pragma unroll
    for (int off = 32; off > 0; off >>= 1) {
        sum += __shfl_down(sum, off);
        sq  += __shfl_down(sq, off);
        cnt += __shfl_down(cnt, off);
    }

    __shared__ float ssum[4], ssq[4], scnt[4];
    const int wave = tid >> 6, lane = tid & 63;
    if (lane == 0) { ssum[wave] = sum; ssq[wave] = sq; scnt[wave] = cnt; }
    __syncthreads();
    if (tid == 0) {
        float ts = 0.f, tq = 0.f, tc = 0.f;
#pragma unroll
        for (int i = 0; i < 4; ++i) { ts += ssum[i]; tq += ssq[i]; tc += scnt[i]; }
        atomicAdd(&ws[d], ts);
        atomicAdd(&ws[DD + d], tq);
        if (d == 0) atomicAdd(&ws[2 * DD], tc);
    }
}

__global__ void __launch_bounds__(256)
finalize_kernel(const float* __restrict__ gamma, const float* __restrict__ beta,
                float* __restrict__ ws) {
    const int d = threadIdx.x;
    const float count = fmaxf(ws[2 * DD], 1.0f);
    const float mean = ws[d] / count;
    float var = ws[DD + d] / count - mean * mean;
    var = fmaxf(var, 0.0f);
    const float scale = rsqrtf(var + EPS) * gamma[d];
    ws[2 * DD + 8 + d] = scale;
    ws[2 * DD + 8 + DD + d] = beta[d] - mean * scale;
}

__global__ void __launch_bounds__(256)
apply_kernel(const float* __restrict__ x, const int* __restrict__ mask,
             const float* __restrict__ ws, float* __restrict__ out) {
    const float* __restrict__ scale = ws + 2 * DD + 8;
    const float* __restrict__ bias  = ws + 2 * DD + 8 + DD;
    const int nvec = TOTAL / 4;            // 8388608
    const int stride = gridDim.x * blockDim.x;
    for (int v = blockIdx.x * blockDim.x + threadIdx.x; v < nvec; v += stride) {
        const int e = v << 2;              // element index
        const int b = e >> 20;             // / DHW
        const int rem = e & (DHW - 1);
        const int d = rem >> 12;           // / 4096
        const int pos = rem & 4095;
        float4 xv = reinterpret_cast<const float4*>(x)[v];
        int4 mv = reinterpret_cast<const int4*>(mask)[(b * HW + pos) >> 2];
        const float s = scale[d], bi = bias[d];
        float4 o;
        o.x = mv.x ? xv.x : xv.x * s + bi;
        o.y = mv.y ? xv.y : xv.y * s + bi;
        o.z = mv.z ? xv.z : xv.z * s + bi;
        o.w = mv.w ? xv.w : xv.w * s + bi;
        reinterpret_cast<float4*>(out)[v] = o;
    }
}

extern "C" void kernel_launch(void* const* d_in, const int* in_sizes, int n_in,
                              void* d_out, int out_size, void* d_ws, size_t ws_size,
                              hipStream_t stream) {
    const float* x     = (const float*)d_in[0];
    const int*   mask  = (const int*)d_in[1];
    const float* gamma = (const float*)d_in[2];
    const float* beta  = (const float*)d_in[3];
    float* out = (float*)d_out;
    float* ws  = (float*)d_ws;

    // zero the accumulator region every call (ws is poisoned, not re-poisoned)
    hipMemsetAsync(ws, 0, (2 * DD + 1) * sizeof(float), stream);

    stats_kernel<<<BB * DD, 256, 0, stream>>>(x, mask, ws);
    finalize_kernel<<<1, 256, 0, stream>>>(gamma, beta, ws);
    apply_kernel<<<2048, 256, 0, stream>>>(x, mask, ws, out);
}

// Round 2
// 70.634 us; speedup vs baseline: 1.1387x; 1.1387x over previous
//
#include <hip/hip_runtime.h>

// Problem constants (from reference setup_inputs): b=32, d=256, h=32, w=128
#define BB 32
#define DD 256
#define HW 4096             // h*w
#define DHW (DD * HW)       // 1048576 = 2^20
#define TOTAL (BB * DHW)    // 33554432
#define NSLICE (BB * DD)    // 8192
#define EPS 1e-5f

// ws layout (floats):
//   [0, 8192)        per-slice sum      (slice = b*256 + d)
//   [8192, 16384)    per-slice sumsq
//   [16384, 16416)   per-b unmasked count
// All slots are fully written by stats_kernel every call -> no zeroing needed.

__global__ void __launch_bounds__(256)
stats_kernel(const float* __restrict__ x, const int* __restrict__ mask,
             float* __restrict__ ws) {
    const int slice = blockIdx.x;          // 8192 slices
    const int b = slice >> 8;
    const int d = slice & 255;
    const float4* xs = reinterpret_cast<const float4*>(
        x + (size_t)b * DHW + (size_t)d * HW);
    const int4* ms = reinterpret_cast<const int4*>(mask + b * HW);
    const int tid = threadIdx.x;

    float sum = 0.f, sq = 0.f, cnt = 0.f;
#pragma unroll
    for (int j = 0; j < 4; ++j) {
        const int v = j * 256 + tid;       // float4 index within the 4096-slice
        float4 xv = xs[v];
        int4 mv = ms[v];
        if (!mv.x) { sum += xv.x; sq += xv.x * xv.x; cnt += 1.f; }
        if (!mv.y) { sum += xv.y; sq += xv.y * xv.y; cnt += 1.f; }
        if (!mv.z) { sum += xv.z; sq += xv.z * xv.z; cnt += 1.f; }
        if (!mv.w) { sum += xv.w; sq += xv.w * xv.w; cnt += 1.f; }
    }

    // wave64 shuffle reduce
#pragma unroll
    for (int off = 32; off > 0; off >>= 1) {
        sum += __shfl_down(sum, off);
        sq  += __shfl_down(sq, off);
        cnt += __shfl_down(cnt, off);
    }

    __shared__ float ssum[4], ssq[4], scnt[4];
    const int wave = tid >> 6, lane = tid & 63;
    if (lane == 0) { ssum[wave] = sum; ssq[wave] = sq; scnt[wave] = cnt; }
    __syncthreads();
    if (tid == 0) {
        float ts = 0.f, tq = 0.f, tc = 0.f;
#pragma unroll
        for (int i = 0; i < 4; ++i) { ts += ssum[i]; tq += ssq[i]; tc += scnt[i]; }
        ws[slice] = ts;                    // disjoint slots: no atomics, no memset
        ws[NSLICE + slice] = tq;
        if (d == 0) ws[2 * NSLICE + b] = tc;
    }
}

__global__ void __launch_bounds__(256)
apply_kernel(const float* __restrict__ x, const int* __restrict__ mask,
             const float* __restrict__ ws, const float* __restrict__ gamma,
             const float* __restrict__ beta, float* __restrict__ out) {
    __shared__ float s_scale[DD], s_bias[DD];
    const int tid = threadIdx.x;

    // Inline finalize: each thread owns one channel, reduces 32 per-b partials
    // (coalesced: consecutive threads -> consecutive addresses; L2-resident).
    float cnt = 0.f;
#pragma unroll
    for (int b = 0; b < BB; ++b) cnt += ws[2 * NSLICE + b];
    cnt = fmaxf(cnt, 1.0f);
    float sum = 0.f, sq = 0.f;
#pragma unroll
    for (int b = 0; b < BB; ++b) {
        sum += ws[b * DD + tid];
        sq  += ws[NSLICE + b * DD + tid];
    }
    const float mean = sum / cnt;
    const float var = fmaxf(sq / cnt - mean * mean, 0.0f);
    const float sc = rsqrtf(var + EPS) * gamma[tid];
    s_scale[tid] = sc;
    s_bias[tid] = beta[tid] - mean * sc;
    __syncthreads();

    const int nvec = TOTAL / 4;            // 8388608 float4s
    const int stride = gridDim.x * blockDim.x;
    for (int v = blockIdx.x * blockDim.x + tid; v < nvec; v += stride) {
        const int e = v << 2;              // element index
        const int b = e >> 20;             // / DHW
        const int rem = e & (DHW - 1);
        const int d = rem >> 12;           // / 4096 (uniform within a wave -> LDS broadcast)
        const int pos = rem & 4095;
        float4 xv = reinterpret_cast<const float4*>(x)[v];
        int4 mv = reinterpret_cast<const int4*>(mask)[(b * HW + pos) >> 2];
        const float s = s_scale[d], bi = s_bias[d];
        float4 o;
        o.x = mv.x ? xv.x : xv.x * s + bi;
        o.y = mv.y ? xv.y : xv.y * s + bi;
        o.z = mv.z ? xv.z : xv.z * s + bi;
        o.w = mv.w ? xv.w : xv.w * s + bi;
        reinterpret_cast<float4*>(out)[v] = o;
    }
}

extern "C" void kernel_launch(void* const* d_in, const int* in_sizes, int n_in,
                              void* d_out, int out_size, void* d_ws, size_t ws_size,
                              hipStream_t stream) {
    const float* x     = (const float*)d_in[0];
    const int*   mask  = (const int*)d_in[1];
    const float* gamma = (const float*)d_in[2];
    const float* beta  = (const float*)d_in[3];
    float* out = (float*)d_out;
    float* ws  = (float*)d_ws;

    stats_kernel<<<NSLICE, 256, 0, stream>>>(x, mask, ws);
    apply_kernel<<<2048, 256, 0, stream>>>(x, mask, ws, gamma, beta, out);
}

// Round 4
// 69.999 us; speedup vs baseline: 1.1490x; 1.0091x over previous
//
#include <hip/hip_runtime.h>

// Problem constants (from reference setup_inputs): b=32, d=256, h=32, w=128
#define BB 32
#define DD 256
#define HW 4096             // h*w
#define DHW (DD * HW)       // 1048576 = 2^20
#define TOTAL (BB * DHW)    // 33554432
#define NSLICE (BB * DD)    // 8192
#define EPS 1e-5f

typedef float floatx4 __attribute__((ext_vector_type(4)));  // native vec for nt-store

// ws layout (floats):
//   [0, 8192)        per-slice sum      (slice = b*256 + d)
//   [8192, 16384)    per-slice sumsq
//   [16384, 16416)   per-b unmasked count
// All slots are fully written by stats_kernel every call -> no zeroing needed.

__global__ void __launch_bounds__(256)
stats_kernel(const float* __restrict__ x, const int* __restrict__ mask,
             float* __restrict__ ws) {
    const int slice = blockIdx.x;          // 8192 slices
    const int b = slice >> 8;
    const int d = slice & 255;
    const float4* xs = reinterpret_cast<const float4*>(
        x + (size_t)b * DHW + (size_t)d * HW);
    const int4* ms = reinterpret_cast<const int4*>(mask + b * HW);
    const int tid = threadIdx.x;

    float sum = 0.f, sq = 0.f, cnt = 0.f;
#pragma unroll
    for (int j = 0; j < 4; ++j) {
        const int v = j * 256 + tid;       // float4 index within the 4096-slice
        float4 xv = xs[v];
        int4 mv = ms[v];
        if (!mv.x) { sum += xv.x; sq += xv.x * xv.x; cnt += 1.f; }
        if (!mv.y) { sum += xv.y; sq += xv.y * xv.y; cnt += 1.f; }
        if (!mv.z) { sum += xv.z; sq += xv.z * xv.z; cnt += 1.f; }
        if (!mv.w) { sum += xv.w; sq += xv.w * xv.w; cnt += 1.f; }
    }

    // wave64 shuffle reduce
#pragma unroll
    for (int off = 32; off > 0; off >>= 1) {
        sum += __shfl_down(sum, off);
        sq  += __shfl_down(sq, off);
        cnt += __shfl_down(cnt, off);
    }

    __shared__ float ssum[4], ssq[4], scnt[4];
    const int wave = tid >> 6, lane = tid & 63;
    if (lane == 0) { ssum[wave] = sum; ssq[wave] = sq; scnt[wave] = cnt; }
    __syncthreads();
    if (tid == 0) {
        float ts = 0.f, tq = 0.f, tc = 0.f;
#pragma unroll
        for (int i = 0; i < 4; ++i) { ts += ssum[i]; tq += ssq[i]; tc += scnt[i]; }
        ws[slice] = ts;                    // disjoint slots: no atomics, no memset
        ws[NSLICE + slice] = tq;
        if (d == 0) ws[2 * NSLICE + b] = tc;
    }
}

__global__ void __launch_bounds__(256)
apply_kernel(const float* __restrict__ x, const int* __restrict__ mask,
             const float* __restrict__ ws, const float* __restrict__ gamma,
             const float* __restrict__ beta, float* __restrict__ out) {
    __shared__ float s_scale[DD], s_bias[DD];
    const int tid = threadIdx.x;

    // Inline finalize: each thread owns one channel, reduces 32 per-b partials
    // (coalesced: consecutive threads -> consecutive addresses; L2-resident).
    float cnt = 0.f;
#pragma unroll
    for (int b = 0; b < BB; ++b) cnt += ws[2 * NSLICE + b];
    cnt = fmaxf(cnt, 1.0f);
    float sum = 0.f, sq = 0.f;
#pragma unroll
    for (int b = 0; b < BB; ++b) {
        sum += ws[b * DD + tid];
        sq  += ws[NSLICE + b * DD + tid];
    }
    const float mean = sum / cnt;
    const float var = fmaxf(sq / cnt - mean * mean, 0.0f);
    const float sc = rsqrtf(var + EPS) * gamma[tid];
    s_scale[tid] = sc;
    s_bias[tid] = beta[tid] - mean * sc;
    __syncthreads();

    const int nvec = TOTAL / 4;            // 8388608 float4s
    const int stride = gridDim.x * blockDim.x;
    floatx4* __restrict__ ov = reinterpret_cast<floatx4*>(out);
    for (int v = blockIdx.x * blockDim.x + tid; v < nvec; v += stride) {
        const int e = v << 2;              // element index
        const int b = e >> 20;             // / DHW
        const int rem = e & (DHW - 1);
        const int d = rem >> 12;           // / 4096 (uniform within a wave -> LDS broadcast)
        const int pos = rem & 4095;
        float4 xv = reinterpret_cast<const float4*>(x)[v];
        int4 mv = reinterpret_cast<const int4*>(mask)[(b * HW + pos) >> 2];
        const float s = s_scale[d], bi = s_bias[d];
        floatx4 o;
        o.x = mv.x ? xv.x : xv.x * s + bi;
        o.y = mv.y ? xv.y : xv.y * s + bi;
        o.z = mv.z ? xv.z : xv.z * s + bi;
        o.w = mv.w ? xv.w : xv.w * s + bi;
        // Non-temporal: don't allocate out in L2/L3, so x (128 MiB) stays
        // resident in the 256 MiB Infinity Cache for this second pass.
        __builtin_nontemporal_store(o, &ov[v]);
    }
}

extern "C" void kernel_launch(void* const* d_in, const int* in_sizes, int n_in,
                              void* d_out, int out_size, void* d_ws, size_t ws_size,
                              hipStream_t stream) {
    const float* x     = (const float*)d_in[0];
    const int*   mask  = (const int*)d_in[1];
    const float* gamma = (const float*)d_in[2];
    const float* beta  = (const float*)d_in[3];
    float* out = (float*)d_out;
    float* ws  = (float*)d_ws;

    stats_kernel<<<NSLICE, 256, 0, stream>>>(x, mask, ws);
    apply_kernel<<<2048, 256, 0, stream>>>(x, mask, ws, gamma, beta, out);
}